// Round 8
// baseline (4855.421 us; speedup 1.0000x reference)
//
#include <hip/hip_runtime.h>

// ---------------------------------------------------------------------------
// Net_SLSTM_TempAtten: 2-layer spiking LSTM, T=512, B=256, I=14, H=512, C=8.
// R8 = R7 (blockIdx groups, MALL-coherent sc0sc1 exchange, agent barrier,
// k-split, register/LDS-resident split-fp16 weights) +
//  - cross-barrier PREFETCH of phase-A fragments: m1[wp] is final before
//    BAR(t); issue its 16 loads in step t's phase-B batch-2 (vmcnt(16),
//    FIFO), hold regs across the boundary -> phase A waits on nothing.
//  - PB_STRIDE 17->18 (writes <=2-way, free) + float2 ew reads (16 reads
//    not 32, <=2-way): R7's 1.42e8 LDS conflicts were self-inflicted.
// Numerics unchanged (R4/R5/R7: absmax 0.0).
// ---------------------------------------------------------------------------

typedef _Float16 half8 __attribute__((ext_vector_type(8)));
typedef float    floatx4 __attribute__((ext_vector_type(4)));
typedef float    float2v __attribute__((ext_vector_type(2)));
typedef int      int4v  __attribute__((ext_vector_type(4)));

union H8 { int4v i; half8 h; };

#define T_STEPS 512
#define HDIM    512
#define ROWS    32
#define HSLICE  16
#define ACT_ELEMS 16384     // 32 rows x 512 h halves = 32 KB per buffer
// buffers: 0=m1hi 1=m1lo 2=spk 3=m2hi 4=m2lo ; x2 parity
#define WS_ACT_OFF 4096
#define WS_PART_OFF (WS_ACT_OFF + 2*5*8*ACT_ELEMS*2)   // 4096 + 2621440
#define WS_PART_BYTES (256*32*8*4)                     // 262144
#define WS_MEMSET_BYTES WS_PART_OFF
#define PB_STRIDE 18        // even: 8B-aligned float2, <=2-way banks (free)

__device__ __forceinline__ float sigm(float v)  { return 1.0f/(1.0f + __expf(-v)); }
__device__ __forceinline__ float tanhf_(float v){ return 1.0f - 2.0f/(__expf(2.0f*v) + 1.0f); }
__device__ __forceinline__ void split16(float v, _Float16& h, _Float16& l) {
  h = (_Float16)v; l = (_Float16)(v - (float)h);
}
__device__ __forceinline__ unsigned pack2(_Float16 a, _Float16 b) {
  unsigned short ua = __builtin_bit_cast(unsigned short, a);
  unsigned short ub = __builtin_bit_cast(unsigned short, b);
  return (unsigned)ua | ((unsigned)ub << 16);
}

// 16B MALL-coherent load (bypass L1+L2). Not ready until a tying s_waitcnt.
#define LDG16(dst, ptr) \
  asm volatile("global_load_dwordx4 %0, %1, off sc0 sc1" : "=v"((dst).i) : "v"(ptr) : "memory")

// MALL-coherent write-through u32 store (R5-proven codegen class).
__device__ __forceinline__ void st_u32(unsigned* p, unsigned v) {
  __hip_atomic_store(p, v, __ATOMIC_RELAXED, __HIP_MEMORY_SCOPE_AGENT);
}

#define MFMA(A,B,C) __builtin_amdgcn_mfma_f32_16x16x32_f16((A),(B),(C),0,0,0)

__global__ __launch_bounds__(256) __attribute__((amdgpu_waves_per_eu(1, 1)))
void slstm_kernel(const float* __restrict__ x,
                  const float* __restrict__ Wih1, const float* __restrict__ Whh1,
                  const float* __restrict__ bih1, const float* __restrict__ bhh1,
                  const float* __restrict__ thr1p,
                  const float* __restrict__ Wih2, const float* __restrict__ Whh2,
                  const float* __restrict__ bih2, const float* __restrict__ bhh2,
                  const float* __restrict__ thr2p,
                  const float* __restrict__ Wfc,  const float* __restrict__ bfc,
                  float* __restrict__ out, unsigned char* __restrict__ ws)
{
  const int tid  = threadIdx.x;
  const int bid  = blockIdx.x;
  const int g    = bid & 7;    // logical group: deterministic slot coverage
  const int cs   = bid >> 3;   // column slice 0..31
  const int wave = tid >> 6;
  const int lane = tid & 63;
  const int l15  = lane & 15;
  const int lg   = lane >> 4;
  const int kr   = lg*8;

  __shared__ _Float16 wIloLds[4*16*64*8];          // 64 KB: Wih2_lo B-frags
  __shared__ float    pbuf[4][128*PB_STRIDE + 16]; // ~37 KB: per-wave partials
  __shared__ _Float16 xstage[ROWS*32];             // 2 KB
  __shared__ float    b2s[64];

  unsigned* cntp  = (unsigned*)ws + (size_t)g*16;  // 64B-spaced barrier counters
  _Float16* actb  = (_Float16*)(ws + WS_ACT_OFF);
  float*    partb = (float*)(ws + WS_PART_OFF);

  // ---- weight B-fragments, split hi/lo; K-split: wave w owns kb=4w..4w+3 ----
  half8 wAh[4][4], wAl[4][4], wIh[4][4], wHh[4][4], wHl[4][4];
#pragma unroll
  for (int q = 0; q < 4; ++q) {
    const int gcq = q*HDIM + cs*HSLICE + l15;
#pragma unroll
    for (int kl = 0; kl < 4; ++kl) {
      const int kb = wave*4 + kl;
      const float* p1 = Whh1 + (size_t)gcq*HDIM + kb*32 + kr;
      const float* p2 = Wih2 + (size_t)gcq*HDIM + kb*32 + kr;
      const float* p3 = Whh2 + (size_t)gcq*HDIM + kb*32 + kr;
      half8 ah, al, ih, il, hh, hl;
#pragma unroll
      for (int j = 0; j < 8; ++j) {
        _Float16 sh, sl;
        split16(p1[j], sh, sl); ah[j] = sh; al[j] = sl;
        split16(p2[j], sh, sl); ih[j] = sh; il[j] = sl;
        split16(p3[j], sh, sl); hh[j] = sh; hl[j] = sl;
      }
      wAh[q][kl] = ah; wAl[q][kl] = al; wIh[q][kl] = ih;
      wHh[q][kl] = hh; wHl[q][kl] = hl;
      *(half8*)&wIloLds[(((wave*4 + kl)*4 + q)*64 + lane)*8] = il;
    }
  }
  // x-path (gate = wave): K=32 padded
  half8 wX1, wX2;
  {
    const int gcx = wave*HDIM + cs*HSLICE + l15;
#pragma unroll
    for (int j = 0; j < 8; ++j) {
      int k = kr + j;
      float v1 = 0.0f, v2 = 0.0f;
      _Float16 h, l;
      if (k < 14)       { split16(Wih1[(size_t)gcx*14 + k], h, l); v1 = (float)h; v2 = (float)l; }
      else if (k == 14) { split16(bih1[gcx] + bhh1[gcx], h, l); v1 = (float)h; }
      else if (k == 15) { split16(bih1[gcx] + bhh1[gcx], h, l); v1 = (float)l; }
      else if (k <= 29) { split16(Wih1[(size_t)gcx*14 + (k - 16)], h, l); v2 = (float)h; }
      wX1[j] = (_Float16)v1; wX2[j] = (_Float16)v2;
    }
  }
  if (tid < 64) {
    int q = tid >> 4, h = tid & 15;
    int gcl = q*HDIM + cs*HSLICE + h;
    b2s[tid] = bih2[gcl] + bhh2[gcl];
  }
  for (int idx = tid; idx < ROWS*32; idx += 256) {
    int k = idx & 31;
    if (k == 14 || k == 15) xstage[idx] = (_Float16)1.0f;
    else if (k >= 30)       xstage[idx] = (_Float16)0.0f;
  }
  __syncthreads();

  const float thr1 = thr1p[0], thr2 = thr2p[0];
  const int eb  = tid >> 3;            // ew row 0..31
  const int ehl = (tid & 7)*2;         // ew local h pair (even)
  const int ehg = cs*HSLICE + ehl;
  const int g16 = ((ehg >> 5)*2 + (eb >> 4))*64 + ((ehg >> 3) & 3)*16 + (eb & 15);
  const int u32i = g16*4 + ((ehg & 7) >> 1);
  const int r0 = tid/14,  k0 = tid%14;
  const int i1 = tid + 256;
  const int r1 = i1/14,   k1 = i1%14;

  float syn1[2] = {0,0}, m1p[2] = {0,0}, syn2[2] = {0,0}, m2p[2] = {0,0};
  float accf[2] = {0,0};
  const float invn = (1.0f - __expf(-0.05f)) / (1.0f - __expf(-0.05f*512.0f));
  int bar_dead = 0;

  // per-wave load offsets for the kb slice
  size_t oA[4][2];
#pragma unroll
  for (int kl = 0; kl < 4; ++kl) {
    const int kb = wave*4 + kl;
    oA[kl][0] = (size_t)(((kb*2 + 0)*64 + lane)*16);
    oA[kl][1] = (size_t)(((kb*2 + 1)*64 + lane)*16);
  }

  // ---- prologue: prefetch phase-A frags for t=0 (parity rp=1, memset zeros)
  H8 fh[4][2], fl[4][2];
  {
    const char* pH = (const char*)(actb + (size_t)((1*5 + 0)*8 + g)*ACT_ELEMS);
    const char* pL = (const char*)(actb + (size_t)((1*5 + 1)*8 + g)*ACT_ELEMS);
#pragma unroll
    for (int kl = 0; kl < 4; ++kl) {
      LDG16(fh[kl][0], pH + oA[kl][0]);  LDG16(fh[kl][1], pH + oA[kl][1]);
      LDG16(fl[kl][0], pL + oA[kl][0]);  LDG16(fl[kl][1], pL + oA[kl][1]);
    }
  }

  for (int t = 0; t < T_STEPS; ++t) {
    const int wp = t & 1, rp = wp ^ 1;

    // ---- stage x_t (plain cached loads; x read-only) ----
    const float* xt = x + ((size_t)t*256 + (size_t)g*ROWS)*14;
    { _Float16 h, l; split16(xt[r0*14 + k0], h, l);
      xstage[r0*32 + k0] = h; xstage[r0*32 + 16 + k0] = l; }
    if (i1 < 448) {
      _Float16 h, l; split16(xt[r1*14 + k1], h, l);
      xstage[r1*32 + k1] = h; xstage[r1*32 + 16 + k1] = l; }
    __syncthreads();

    // ================= phase A: gates1 partials (frags prefetched) =========
    floatx4 acc[4][2];
#pragma unroll
    for (int q = 0; q < 4; ++q) { acc[q][0] = (floatx4){0,0,0,0}; acc[q][1] = (floatx4){0,0,0,0}; }
    {  // x contribution (wave == gate)
      half8 xa0 = *(const half8*)&xstage[l15*32 + kr];
      half8 xa1 = *(const half8*)&xstage[(16 + l15)*32 + kr];
      acc[wave][0] = MFMA(xa0, wX1, acc[wave][0]);  acc[wave][1] = MFMA(xa1, wX1, acc[wave][1]);
      acc[wave][0] = MFMA(xa0, wX2, acc[wave][0]);  acc[wave][1] = MFMA(xa1, wX2, acc[wave][1]);
    }
    asm volatile("s_waitcnt vmcnt(0)"   // prefetched a phase ago: ~free
      : "+v"(fh[0][0].i), "+v"(fh[0][1].i), "+v"(fl[0][0].i), "+v"(fl[0][1].i),
        "+v"(fh[1][0].i), "+v"(fh[1][1].i), "+v"(fl[1][0].i), "+v"(fl[1][1].i),
        "+v"(fh[2][0].i), "+v"(fh[2][1].i), "+v"(fl[2][0].i), "+v"(fl[2][1].i),
        "+v"(fh[3][0].i), "+v"(fh[3][1].i), "+v"(fl[3][0].i), "+v"(fl[3][1].i)
      : : "memory");
#pragma unroll
    for (int kl = 0; kl < 4; ++kl)
#pragma unroll
      for (int q = 0; q < 4; ++q) {
        acc[q][0] = MFMA(fh[kl][0].h, wAh[q][kl], acc[q][0]);
        acc[q][1] = MFMA(fh[kl][1].h, wAh[q][kl], acc[q][1]);
        acc[q][0] = MFMA(fh[kl][0].h, wAl[q][kl], acc[q][0]);
        acc[q][1] = MFMA(fh[kl][1].h, wAl[q][kl], acc[q][1]);
        acc[q][0] = MFMA(fl[kl][0].h, wAh[q][kl], acc[q][0]);
        acc[q][1] = MFMA(fl[kl][1].h, wAh[q][kl], acc[q][1]);
      }
#pragma unroll
    for (int q = 0; q < 4; ++q)
#pragma unroll
      for (int tl = 0; tl < 2; ++tl)
#pragma unroll
        for (int p = 0; p < 4; ++p)
          pbuf[wave][(q*32 + tl*16 + lg*4 + p)*PB_STRIDE + l15] = acc[q][tl][p];
    __syncthreads();

    // ---- ew1: float2 partial sums, gate math, MALL u32 stores ----
    {
      unsigned* m1hW = (unsigned*)(actb + (size_t)((wp*5 + 0)*8 + g)*ACT_ELEMS);
      unsigned* m1lW = (unsigned*)(actb + (size_t)((wp*5 + 1)*8 + g)*ACT_ELEMS);
      unsigned* spW  = (unsigned*)(actb + (size_t)((wp*5 + 2)*8 + g)*ACT_ELEMS);
      float2v pi2 = {0,0}, pf2 = {0,0}, pg2 = {0,0}, po2 = {0,0};
#pragma unroll
      for (int w = 0; w < 4; ++w) {
        pi2 += *(const float2v*)&pbuf[w][(0*32 + eb)*PB_STRIDE + ehl];
        pf2 += *(const float2v*)&pbuf[w][(1*32 + eb)*PB_STRIDE + ehl];
        pg2 += *(const float2v*)&pbuf[w][(2*32 + eb)*PB_STRIDE + ehl];
        po2 += *(const float2v*)&pbuf[w][(3*32 + eb)*PB_STRIDE + ehl];
      }
      _Float16 mh[2], ml[2], sp[2];
#pragma unroll
      for (int c = 0; c < 2; ++c) {
        float iv = sigm(pi2[c]), fv = sigm(pf2[c]), gv = tanhf_(pg2[c]), ov = sigm(po2[c]);
        float cnew = fv*syn1[c] + iv*gv;
        syn1[c] = cnew;
        float hnew = ov*tanhf_(cnew);
        float m1 = hnew - ((m1p[c] > thr1) ? thr1 : 0.0f);   // detached reset
        m1p[c] = m1;
        split16(m1, mh[c], ml[c]);
        sp[c] = ((m1 - thr1) > 0.0f) ? (_Float16)1.0f : (_Float16)0.0f;
      }
      st_u32(m1hW + u32i, pack2(mh[0], mh[1]));
      st_u32(m1lW + u32i, pack2(ml[0], ml[1]));
      st_u32(spW  + u32i, pack2(sp[0], sp[1]));
    }

    // ---- group barrier (agent scope); per-wave store drain ----
    asm volatile("s_waitcnt vmcnt(0)" ::: "memory");
    __syncthreads();
    if (tid == 0 && !bar_dead) {
      __hip_atomic_fetch_add(cntp, 1u, __ATOMIC_RELAXED, __HIP_MEMORY_SCOPE_AGENT);
      unsigned target = 32u*(unsigned)(t + 1);
      int tries = 0;
      while (__hip_atomic_load(cntp, __ATOMIC_RELAXED, __HIP_MEMORY_SCOPE_AGENT) < target) {
        __builtin_amdgcn_s_sleep(1);
        if (++tries > (1 << 20)) { bar_dead = 1; break; }   // anti-hang fuse
      }
    }
    __syncthreads();
    __atomic_signal_fence(__ATOMIC_SEQ_CST);

    // ================= phase B: gates2 partials ============================
    const char* baseS  = (const char*)(actb + (size_t)((wp*5 + 2)*8 + g)*ACT_ELEMS);
    const char* base2H = (const char*)(actb + (size_t)((rp*5 + 3)*8 + g)*ACT_ELEMS);
    const char* base2L = (const char*)(actb + (size_t)((rp*5 + 4)*8 + g)*ACT_ELEMS);
    // next step's phase-A buffers: m1[wp], final since before this barrier
    const char* nH = (const char*)(actb + (size_t)((wp*5 + 0)*8 + g)*ACT_ELEMS);
    const char* nL = (const char*)(actb + (size_t)((wp*5 + 1)*8 + g)*ACT_ELEMS);
#pragma unroll
    for (int q = 0; q < 4; ++q) { acc[q][0] = (floatx4){0,0,0,0}; acc[q][1] = (floatx4){0,0,0,0}; }

    H8 sb[2][2], mbh[2][2], mbl[2][2];
    // batch 1: kl = 0,1
#pragma unroll
    for (int kc = 0; kc < 2; ++kc) {
      LDG16(sb[kc][0],  baseS  + oA[kc][0]);  LDG16(sb[kc][1],  baseS  + oA[kc][1]);
      LDG16(mbh[kc][0], base2H + oA[kc][0]);  LDG16(mbh[kc][1], base2H + oA[kc][1]);
      LDG16(mbl[kc][0], base2L + oA[kc][0]);  LDG16(mbl[kc][1], base2L + oA[kc][1]);
    }
    asm volatile("s_waitcnt vmcnt(0)"
      : "+v"(sb[0][0].i), "+v"(sb[0][1].i), "+v"(mbh[0][0].i), "+v"(mbh[0][1].i),
        "+v"(mbl[0][0].i), "+v"(mbl[0][1].i),
        "+v"(sb[1][0].i), "+v"(sb[1][1].i), "+v"(mbh[1][0].i), "+v"(mbh[1][1].i),
        "+v"(mbl[1][0].i), "+v"(mbl[1][1].i)
      : : "memory");
#pragma unroll
    for (int kc = 0; kc < 2; ++kc) {
      const int kl = kc;
#pragma unroll
      for (int q = 0; q < 4; ++q) {
        half8 wIl = *(const half8*)&wIloLds[(((wave*4 + kl)*4 + q)*64 + lane)*8];
        acc[q][0] = MFMA(sb[kc][0].h,  wIh[q][kl], acc[q][0]);
        acc[q][1] = MFMA(sb[kc][1].h,  wIh[q][kl], acc[q][1]);
        acc[q][0] = MFMA(sb[kc][0].h,  wIl,        acc[q][0]);
        acc[q][1] = MFMA(sb[kc][1].h,  wIl,        acc[q][1]);
        acc[q][0] = MFMA(mbh[kc][0].h, wHh[q][kl], acc[q][0]);
        acc[q][1] = MFMA(mbh[kc][1].h, wHh[q][kl], acc[q][1]);
        acc[q][0] = MFMA(mbh[kc][0].h, wHl[q][kl], acc[q][0]);
        acc[q][1] = MFMA(mbh[kc][1].h, wHl[q][kl], acc[q][1]);
        acc[q][0] = MFMA(mbl[kc][0].h, wHh[q][kl], acc[q][0]);
        acc[q][1] = MFMA(mbl[kc][1].h, wHh[q][kl], acc[q][1]);
      }
    }
    // batch 2 (kl = 2,3) + PREFETCH of next step's 16 phase-A frags
#pragma unroll
    for (int kc = 0; kc < 2; ++kc) {
      LDG16(sb[kc][0],  baseS  + oA[2+kc][0]);  LDG16(sb[kc][1],  baseS  + oA[2+kc][1]);
      LDG16(mbh[kc][0], base2H + oA[2+kc][0]);  LDG16(mbh[kc][1], base2H + oA[2+kc][1]);
      LDG16(mbl[kc][0], base2L + oA[2+kc][0]);  LDG16(mbl[kc][1], base2L + oA[2+kc][1]);
    }
#pragma unroll
    for (int kl = 0; kl < 4; ++kl) {
      LDG16(fh[kl][0], nH + oA[kl][0]);  LDG16(fh[kl][1], nH + oA[kl][1]);
      LDG16(fl[kl][0], nL + oA[kl][0]);  LDG16(fl[kl][1], nL + oA[kl][1]);
    }
    asm volatile("s_waitcnt vmcnt(16)"   // FIFO: batch-2's 12 oldest complete
      : "+v"(sb[0][0].i), "+v"(sb[0][1].i), "+v"(mbh[0][0].i), "+v"(mbh[0][1].i),
        "+v"(mbl[0][0].i), "+v"(mbl[0][1].i),
        "+v"(sb[1][0].i), "+v"(sb[1][1].i), "+v"(mbh[1][0].i), "+v"(mbh[1][1].i),
        "+v"(mbl[1][0].i), "+v"(mbl[1][1].i)
      : : "memory");
#pragma unroll
    for (int kc = 0; kc < 2; ++kc) {
      const int kl = 2 + kc;
#pragma unroll
      for (int q = 0; q < 4; ++q) {
        half8 wIl = *(const half8*)&wIloLds[(((wave*4 + kl)*4 + q)*64 + lane)*8];
        acc[q][0] = MFMA(sb[kc][0].h,  wIh[q][kl], acc[q][0]);
        acc[q][1] = MFMA(sb[kc][1].h,  wIh[q][kl], acc[q][1]);
        acc[q][0] = MFMA(sb[kc][0].h,  wIl,        acc[q][0]);
        acc[q][1] = MFMA(sb[kc][1].h,  wIl,        acc[q][1]);
        acc[q][0] = MFMA(mbh[kc][0].h, wHh[q][kl], acc[q][0]);
        acc[q][1] = MFMA(mbh[kc][1].h, wHh[q][kl], acc[q][1]);
        acc[q][0] = MFMA(mbh[kc][0].h, wHl[q][kl], acc[q][0]);
        acc[q][1] = MFMA(mbh[kc][1].h, wHl[q][kl], acc[q][1]);
        acc[q][0] = MFMA(mbl[kc][0].h, wHh[q][kl], acc[q][0]);
        acc[q][1] = MFMA(mbl[kc][1].h, wHh[q][kl], acc[q][1]);
      }
    }
#pragma unroll
    for (int q = 0; q < 4; ++q)
#pragma unroll
      for (int tl = 0; tl < 2; ++tl)
#pragma unroll
        for (int p = 0; p < 4; ++p)
          pbuf[wave][(q*32 + tl*16 + lg*4 + p)*PB_STRIDE + l15] = acc[q][tl][p];
    __syncthreads();

    // ---- ew2 + temporal-attention accumulation ----
    float wt = __expf(0.05f*(float)(t + 1 - T_STEPS)) * invn;
    {
      unsigned* m2hW = (unsigned*)(actb + (size_t)((wp*5 + 3)*8 + g)*ACT_ELEMS);
      unsigned* m2lW = (unsigned*)(actb + (size_t)((wp*5 + 4)*8 + g)*ACT_ELEMS);
      float2v pi2, pf2, pg2, po2;
      pi2 = *(const float2v*)&b2s[0*16 + ehl];
      pf2 = *(const float2v*)&b2s[1*16 + ehl];
      pg2 = *(const float2v*)&b2s[2*16 + ehl];
      po2 = *(const float2v*)&b2s[3*16 + ehl];
#pragma unroll
      for (int w = 0; w < 4; ++w) {
        pi2 += *(const float2v*)&pbuf[w][(0*32 + eb)*PB_STRIDE + ehl];
        pf2 += *(const float2v*)&pbuf[w][(1*32 + eb)*PB_STRIDE + ehl];
        pg2 += *(const float2v*)&pbuf[w][(2*32 + eb)*PB_STRIDE + ehl];
        po2 += *(const float2v*)&pbuf[w][(3*32 + eb)*PB_STRIDE + ehl];
      }
      _Float16 mh[2], ml[2];
#pragma unroll
      for (int c = 0; c < 2; ++c) {
        float iv = sigm(pi2[c]), fv = sigm(pf2[c]), gv = tanhf_(pg2[c]), ov = sigm(po2[c]);
        float cnew = fv*syn2[c] + iv*gv;
        syn2[c] = cnew;
        float hnew = ov*tanhf_(cnew);
        float m2 = hnew - ((m2p[c] > thr2) ? thr2 : 0.0f);
        m2p[c] = m2;
        accf[c] += wt * m2;
        split16(m2, mh[c], ml[c]);
      }
      st_u32(m2hW + u32i, pack2(mh[0], mh[1]));
      st_u32(m2lW + u32i, pack2(ml[0], ml[1]));
    }
    // m2 stores drain at next step's barrier (consumed after it)
  }

  // ---- epilogue: final_mem @ Wfc^T + bfc ----
  float part[8];
#pragma unroll
  for (int c = 0; c < 8; ++c)
    part[c] = accf[0]*Wfc[c*HDIM + ehg] + accf[1]*Wfc[c*HDIM + ehg + 1];
#pragma unroll
  for (int off = 1; off < 8; off <<= 1)
#pragma unroll
    for (int c = 0; c < 8; ++c)
      part[c] += __shfl_xor(part[c], off, 64);
  {
    int c = tid & 7;
    __hip_atomic_store(&partb[((size_t)(g*32 + cs)*32 + (size_t)eb)*8 + c], part[c],
                       __ATOMIC_RELAXED, __HIP_MEMORY_SCOPE_AGENT);
  }
  asm volatile("s_waitcnt vmcnt(0)" ::: "memory");
  __syncthreads();
  if (tid == 0 && !bar_dead) {
    __hip_atomic_fetch_add(cntp, 1u, __ATOMIC_RELAXED, __HIP_MEMORY_SCOPE_AGENT);
    unsigned target = 32u*513u;
    int tries = 0;
    while (__hip_atomic_load(cntp, __ATOMIC_RELAXED, __HIP_MEMORY_SCOPE_AGENT) < target) {
      __builtin_amdgcn_s_sleep(1);
      if (++tries > (1 << 20)) break;
    }
  }
  __syncthreads();
  __atomic_signal_fence(__ATOMIC_SEQ_CST);

  if (cs == 0) {   // wg 0 of each group reduces its group's 32x8 outputs
    int b = tid >> 3, c = tid & 7;
    float s = bfc[c];
#pragma unroll 4
    for (int jj = 0; jj < 32; ++jj)
      s += __hip_atomic_load(&partb[((size_t)(g*32 + jj)*32 + (size_t)b)*8 + c],
                             __ATOMIC_RELAXED, __HIP_MEMORY_SCOPE_AGENT);
    out[(g*ROWS + b)*8 + c] = s;
  }
}

extern "C" void kernel_launch(void* const* d_in, const int* in_sizes, int n_in,
                              void* d_out, int out_size, void* d_ws, size_t ws_size,
                              hipStream_t stream) {
  (void)in_sizes; (void)n_in;
  const float* x    = (const float*)d_in[0];
  const float* Wih1 = (const float*)d_in[1];
  const float* Whh1 = (const float*)d_in[2];
  const float* bih1 = (const float*)d_in[3];
  const float* bhh1 = (const float*)d_in[4];
  const float* thr1 = (const float*)d_in[5];
  const float* Wih2 = (const float*)d_in[6];
  const float* Whh2 = (const float*)d_in[7];
  const float* bih2 = (const float*)d_in[8];
  const float* bhh2 = (const float*)d_in[9];
  const float* thr2 = (const float*)d_in[10];
  const float* Wfc  = (const float*)d_in[11];
  const float* bfc  = (const float*)d_in[12];
  float* out = (float*)d_out;
  unsigned char* ws = (unsigned char*)d_ws;

  if (ws_size < (size_t)(WS_PART_OFF + WS_PART_BYTES)) {
    hipError_t e1 = hipMemsetAsync(d_out, 0x7f, (size_t)out_size*4, stream);
    (void)e1;
    return;
  }
  hipError_t e2 = hipMemsetAsync(d_ws, 0, WS_MEMSET_BYTES, stream);
  (void)e2;

  slstm_kernel<<<dim3(256), dim3(256), 0, stream>>>(
      x, Wih1, Whh1, bih1, bhh1, thr1,
      Wih2, Whh2, bih2, bhh2, thr2, Wfc, bfc, out, ws);
}